// Round 1
// baseline (147.678 us; speedup 1.0000x reference)
//
#include <hip/hip_runtime.h>
#include <hip/hip_bf16.h>

#define N_NODES 500000
#define N_FEAT 125
#define HID 128
#define OUTD 64
#define N_GRAPHS 4096
#define N_TYPES 100
#define WTILE 32
#define NTILES32 (N_NODES / WTILE)        /* 15625 exact — no tail handling */
#define NBLOCKS 256
#define NWAVES 8
#define WPAD 136    /* bf16 row stride: 16B-aligned; 68 dwords == 4 mod 32 banks */

typedef float f32x4 __attribute__((ext_vector_type(4)));
typedef short s16x8 __attribute__((ext_vector_type(8)));

// LDS layout (bytes)
#define OFF_T 0
#define SZ_T (N_TYPES * WPAD * 2)                  // 27200
#define OFF_W2 (OFF_T + SZ_T)
#define OFF_W3 (OFF_W2 + HID * WPAD * 2)           // +34816
#define OFF_B2 (OFF_W3 + OUTD * WPAD * 2)          // +17408
#define OFF_SCR (OFF_B2 + HID * 4)                 // +512  -> 79936
#define SCR_BYTES (WTILE * WPAD * 2)               // 8704/wave (h2 round-trip only)
#define LDS_BYTES (OFF_SCR + NWAVES * SCR_BYTES)   // 149568 (<= 163840)

// ws layout (bytes)
#define WS_GSUM 0
#define WS_GCNT ((size_t)N_GRAPHS * OUTD * 4)      // 1048576
#define WS_T    (WS_GCNT + (size_t)N_GRAPHS * 4)   // 1064960
#define WS_ZERO WS_T                               // bytes to memset (gsum+gcnt)

__device__ __forceinline__ unsigned short f2bf(float f) {
  union { float f; unsigned u; } v; v.f = f;
  unsigned r = v.u + 0x7FFFu + ((v.u >> 16) & 1u);  // RNE
  return (unsigned short)(r >> 16);
}
__device__ __forceinline__ float bf2f(unsigned short u) {
  union { unsigned u; float f; } v; v.u = ((unsigned)u) << 16;
  return v.f;
}
__device__ __forceinline__ unsigned pk2bf(float a, float b) {
  __hip_bfloat162 h = __float22bfloat162_rn(float2{a, b});   // .x -> low 16, .y -> high 16
  union { __hip_bfloat162 h; unsigned u; } v; v.h = h;
  return v.u;
}

// Wave-local LDS ordering fence (DS pipe is in-order per wave; this stops the
// compiler from reordering may-alias LDS ops). Proven correct in R3.
__device__ __forceinline__ void wavefence() {
  __builtin_amdgcn_sched_barrier(0);
  __builtin_amdgcn_wave_barrier();
  __builtin_amdgcn_sched_barrier(0);
}

// ---- pre-pass: T[100][128] = emb @ W1[3:,:] + b1  (fp32 math, bf16 store) ----
extern "C" __global__ void gnn_prep(const float* __restrict__ emb,
                                    const float* __restrict__ W1,
                                    const float* __restrict__ b1,
                                    unsigned short* __restrict__ Tg)
{
  const int g = blockIdx.x, j = threadIdx.x;     // 100 blocks x 128 threads
  float acc = b1[j];
  const float* er = emb + g * N_FEAT;
  for (int k = 0; k < N_FEAT; ++k)
    acc = fmaf(er[k], W1[(3 + k) * HID + j], acc);   // W1 read coalesced over j
  Tg[g * HID + j] = f2bf(acc);
}

extern "C" __global__ void __launch_bounds__(512, 2)
gnn_main(const float* __restrict__ pos, const int* __restrict__ z,
         const int* __restrict__ batch, const unsigned short* __restrict__ Tg,
         const float* __restrict__ W1, const float* __restrict__ W2,
         const float* __restrict__ b2, const float* __restrict__ W3,
         float* __restrict__ gsum, int* __restrict__ gcnt)
{
  extern __shared__ char lds[];
  unsigned short* Tl  = (unsigned short*)(lds + OFF_T);
  unsigned short* w2t = (unsigned short*)(lds + OFF_W2);
  unsigned short* w3t = (unsigned short*)(lds + OFF_W3);
  float* bias2 = (float*)(lds + OFF_B2);

  const int t = threadIdx.x;

  // ---- stage once per block ----
  for (int i = t; i < N_TYPES * HID; i += 512) {   // T: bf16, padded rows
    int g = i >> 7, f = i & 127;
    Tl[g * WPAD + f] = Tg[i];
  }
  for (int i = t; i < HID * HID; i += 512) {       // W2^T [n][k] bf16
    int k = i >> 7, n = i & 127;
    w2t[n * WPAD + k] = f2bf(W2[i]);
  }
  for (int i = t; i < HID * OUTD; i += 512) {      // W3^T [n][k] bf16
    int k = i >> 6, n = i & 63;
    w3t[n * WPAD + k] = f2bf(W3[i]);
  }
  if (t < HID) bias2[t] = b2[t];

  const int wave = t >> 6, lane = t & 63, quad = lane >> 4, l15 = lane & 15;
  unsigned short* xs = (unsigned short*)(lds + OFF_SCR + wave * SCR_BYTES);

  // ---- per-lane W1 pos-row coefficients, fp32, tile-invariant (96 VGPRs) ----
  float w1r[3][4][8];
  #pragma unroll
  for (int c = 0; c < 3; ++c)
    #pragma unroll
    for (int k = 0; k < 4; ++k)
      #pragma unroll
      for (int j = 0; j < 8; ++j)
        w1r[c][k][j] = W1[c * HID + k * 32 + quad * 8 + j];

  __syncthreads();   // the ONLY block-wide barrier

  const int gwave = blockIdx.x * NWAVES + wave;

  for (int tile = gwave; tile < NTILES32; tile += NBLOCKS * NWAVES) {
    const int base = tile * WTILE;

    // per-column graph ids for the in-register pool (quads duplicate, cache-broadcast)
    const int id0 = batch[base + l15];
    const int id1 = batch[base + 16 + l15];

    // ---- layer 1 in VALU, directly into MFMA B-fragments (x^T operand) ----
    // h1[node][f] = relu(T[z][f] + px*W1r0[f] + py*W1r1[f] + pz*W1r2[f])
    s16x8 a[2][4];
    #pragma unroll
    for (int m = 0; m < 2; ++m) {
      const int node = base + m * 16 + l15;        // always < N_NODES (exact tiles)
      const int zi = z[node];
      const float px = pos[node * 3], py = pos[node * 3 + 1], pz = pos[node * 3 + 2];
      const unsigned short* Tr = Tl + zi * WPAD;
      #pragma unroll
      for (int k = 0; k < 4; ++k) {
        s16x8 tf = *(const s16x8*)(Tr + k * 32 + quad * 8);
        s16x8 fr;
        #pragma unroll
        for (int j = 0; j < 8; j += 2) {
          float v0 = bf2f((unsigned short)tf[j])
                   + px * w1r[0][k][j] + py * w1r[1][k][j] + pz * w1r[2][k][j];
          float v1 = bf2f((unsigned short)tf[j + 1])
                   + px * w1r[0][k][j + 1] + py * w1r[1][k][j + 1] + pz * w1r[2][k][j + 1];
          ((unsigned*)&fr)[j >> 1] = pk2bf(fmaxf(v0, 0.f), fmaxf(v1, 0.f));
        }
        a[m][k] = fr;
      }
    }

    // ---- layer 2: D = W2^T(A) x h1^T(B) -> C: row=out-feature, col=node ----
    f32x4 acc[8][2] = {};
    __builtin_amdgcn_s_setprio(1);
    #pragma unroll
    for (int oi = 0; oi < 8; ++oi)
      #pragma unroll
      for (int k = 0; k < 4; ++k) {
        s16x8 w = *(const s16x8*)(w2t + (oi * 16 + l15) * WPAD + k * 32 + quad * 8);
        acc[oi][0] = __builtin_amdgcn_mfma_f32_16x16x32_bf16(w, a[0][k], acc[oi][0], 0, 0, 0);
        acc[oi][1] = __builtin_amdgcn_mfma_f32_16x16x32_bf16(w, a[1][k], acc[oi][1], 0, 0, 0);
      }
    __builtin_amdgcn_s_setprio(0);
    // epilogue 2: 4 consecutive features per lane -> packed b64 writes
    #pragma unroll
    for (int oi = 0; oi < 8; ++oi) {
      const int f0 = oi * 16 + quad * 4;
      f32x4 bv = *(const f32x4*)(bias2 + f0);
      #pragma unroll
      for (int m = 0; m < 2; ++m) {
        unsigned lo = pk2bf(fmaxf(acc[oi][m][0] + bv[0], 0.f),
                            fmaxf(acc[oi][m][1] + bv[1], 0.f));
        unsigned hi = pk2bf(fmaxf(acc[oi][m][2] + bv[2], 0.f),
                            fmaxf(acc[oi][m][3] + bv[3], 0.f));
        *(uint2*)(xs + (m * 16 + l15) * WPAD + f0) = uint2{lo, hi};
      }
    }
    wavefence();
    #pragma unroll
    for (int m = 0; m < 2; ++m)
      #pragma unroll
      for (int k = 0; k < 4; ++k)
        a[m][k] = *(const s16x8*)(xs + (m * 16 + l15) * WPAD + k * 32 + quad * 8);
    wavefence();

    // ---- layer 3: D = W3^T x h2^T -> row=out-dim, col=node; b3 folded into finalize
    f32x4 acc3[4][2] = {};
    __builtin_amdgcn_s_setprio(1);
    #pragma unroll
    for (int oi = 0; oi < 4; ++oi)
      #pragma unroll
      for (int k = 0; k < 4; ++k) {
        s16x8 w = *(const s16x8*)(w3t + (oi * 16 + l15) * WPAD + k * 32 + quad * 8);
        acc3[oi][0] = __builtin_amdgcn_mfma_f32_16x16x32_bf16(w, a[0][k], acc3[oi][0], 0, 0, 0);
        acc3[oi][1] = __builtin_amdgcn_mfma_f32_16x16x32_bf16(w, a[1][k], acc3[oi][1], 0, 0, 0);
      }
    __builtin_amdgcn_s_setprio(0);

    // ---- pool: in-register segmented reduce (batch sorted; avg 1.26 runs/tile)
    // acc3 layout: col(node)=l15 (+16*m), row(out-dim)=oi*16+quad*4+r.
    // Reduction over nodes = cndmask over m + xor-butterfly over l15 (lane bits 0-3).
    {
      int done = 0;
      while (done < 32) {                          // wave-uniform loop
        const int g = __builtin_amdgcn_readfirstlane(batch[base + done]);
        const bool m0 = (id0 == g), m1 = (id1 == g);
        float red[4][4];
        #pragma unroll
        for (int oi = 0; oi < 4; ++oi)
          #pragma unroll
          for (int r = 0; r < 4; ++r)
            red[oi][r] = (m0 ? acc3[oi][0][r] : 0.f) + (m1 ? acc3[oi][1][r] : 0.f);
        #pragma unroll
        for (int s = 1; s <= 8; s <<= 1)
          #pragma unroll
          for (int oi = 0; oi < 4; ++oi)
            #pragma unroll
            for (int r = 0; r < 4; ++r)
              red[oi][r] += __shfl_xor(red[oi][r], s, 64);
        const int cnt = (int)((__popcll(__ballot(m0)) + __popcll(__ballot(m1))) >> 2);
        if (l15 == 0) {                            // 4 lanes (one per quad) fire atomics
          #pragma unroll
          for (int oi = 0; oi < 4; ++oi)
            #pragma unroll
            for (int r = 0; r < 4; ++r)
              atomicAdd(&gsum[g * OUTD + oi * 16 + quad * 4 + r], red[oi][r]);
        }
        if (lane == 0) atomicAdd(&gcnt[g], cnt);
        done += cnt;                               // cnt >= 1: column `done` matches g
      }
    }
    // no LDS touched since the post-reload fence -> next tile's epi2 writes are safe
  }
}

extern "C" __global__ void gnn_finalize(const float* __restrict__ gsum,
                                        const int* __restrict__ gcnt,
                                        const float* __restrict__ b3,
                                        float* __restrict__ out)
{
  int i = blockIdx.x * 256 + threadIdx.x;
  if (i < N_GRAPHS * OUTD) {
    int g = i >> 6, o = i & 63;
    int c = gcnt[g];
    out[i] = (c > 0) ? (gsum[i] / (float)c + b3[o]) : 0.f;
  }
}

extern "C" void kernel_launch(void* const* d_in, const int* in_sizes, int n_in,
                              void* d_out, int out_size, void* d_ws, size_t ws_size,
                              hipStream_t stream) {
  const float* pos  = (const float*)d_in[0];
  const int*   z    = (const int*)d_in[1];
  const int*   batch= (const int*)d_in[2];
  const float* emb  = (const float*)d_in[3];
  const float* W1   = (const float*)d_in[4];
  const float* b1   = (const float*)d_in[5];
  const float* W2   = (const float*)d_in[6];
  const float* b2   = (const float*)d_in[7];
  const float* W3   = (const float*)d_in[8];
  const float* b3   = (const float*)d_in[9];

  float* gsum = (float*)d_ws;
  int*   gcnt = (int*)((char*)d_ws + WS_GCNT);
  unsigned short* Tg = (unsigned short*)((char*)d_ws + WS_T);

  hipMemsetAsync(d_ws, 0, WS_ZERO, stream);

  hipLaunchKernelGGL(gnn_prep, dim3(N_TYPES), dim3(HID), 0, stream, emb, W1, b1, Tg);

  hipFuncSetAttribute((const void*)gnn_main,
                      hipFuncAttributeMaxDynamicSharedMemorySize, LDS_BYTES);
  hipLaunchKernelGGL(gnn_main, dim3(NBLOCKS), dim3(512), LDS_BYTES, stream,
                     pos, z, batch, Tg, W1, W2, b2, W3, gsum, gcnt);
  hipLaunchKernelGGL(gnn_finalize, dim3((N_GRAPHS * OUTD + 255) / 256), dim3(256), 0, stream,
                     gsum, gcnt, b3, (float*)d_out);
}